// Round 6
// baseline (64.532 us; speedup 1.0000x reference)
//
#include <hip/hip_runtime.h>

#define NT 320

__device__ __forceinline__ int refl(int i, int n) {
    i = (i < 0) ? (-i - 1) : i;
    i = (i >= n) ? (2 * n - 1 - i) : i;
    return i;
}

// Persistent-pipelined fused 2D DWT level. 32x32 output tile.
// out[i] = sum_k f[k] * x[refl(2i+1-k)] on both axes.
// Each block owns a contiguous (y-fastest) run of tiles; phase-A loads for
// tile t+1 are issued before phase B of tile t (latency hidden). Single LDS
// buffer: conv(t+1) writes only after the loop-end barrier.
__global__ __launch_bounds__(NT)
void dwt2_fused(const float* __restrict__ in, int n, int ldin, int inb,
                int m, int nty, int ntx, int ntiles,
                float* __restrict__ oA, int ldA, int Ab,
                float* __restrict__ oH, float* __restrict__ oV,
                float* __restrict__ oD)
{
    constexpr float LOF[8] = {
        -0.010597401784997278f,  0.032883011666982945f,
         0.030841381835986965f, -0.18703481171888114f,
        -0.02798376941698385f,   0.6308807679295904f,
         0.7148465705525415f,    0.23037781330885523f };
    constexpr float HIF[8] = {
        -0.23037781330885523f,   0.7148465705525415f,
        -0.6308807679295904f,   -0.02798376941698385f,
         0.18703481171888114f,   0.030841381835986965f,
        -0.032883011666982945f, -0.010597401784997278f };

    __shared__ float s[70][66];   // lo/hi interleaved: s[t][2c]=lo, s[t][2c+1]=hi

    const int tid = threadIdx.x;
    const int G = gridDim.x;

    // XCD-chunked bijective remap (m204): XCD x owns a contiguous tile range.
    const int q = G >> 3, r = G & 7;
    const int xcd = blockIdx.x & 7, pos = blockIdx.x >> 3;
    const int gp = xcd * q + (xcd < r ? xcd : r) + pos;

    // contiguous tile chunk for this block (products < 2^31)
    const int t_lo = (gp * ntiles) / G;
    const int t_hi = ((gp + 1) * ntiles) / G;

    // phase-A item: 8 output cols. 280 items: row a_tr (0..69), oct a_oc8 (0..3)
    const bool hasA = (tid < 280);
    const int a_tr = tid >> 2, a_oc8 = tid & 3;

    float va[24];   // prefetched input window (24 floats, 6 aligned float4)

    // ---- prologue: load phase-A window for first tile ----
    {
        const int t = t_lo;
        if (hasA) {
            const int ty = t % nty; const int u2 = t / nty;
            const int tx = u2 % ntx; const int b = u2 / ntx;
            const float* Ain = in + b * inb;
            const int rr = 2 * (ty * 32) - 6 + a_tr;
            const int cw = 2 * (tx * 32) - 8 + 16 * a_oc8;
            if (rr >= 0 && rr < n && cw >= 0 && cw + 23 < n) {
                const float* p = Ain + rr * ldin + cw;
                #pragma unroll
                for (int j = 0; j < 6; ++j) {
                    const float4 t4 = *(const float4*)(p + 4 * j);
                    va[4*j] = t4.x; va[4*j+1] = t4.y; va[4*j+2] = t4.z; va[4*j+3] = t4.w;
                }
            } else {
                const float* row = Ain + refl(rr, n) * ldin;
                #pragma unroll
                for (int u = 0; u < 24; ++u) va[u] = row[refl(cw + u, n)];
            }
        }
    }

    for (int t = t_lo; t < t_hi; ++t) {
        const int ty = t % nty; const int u2 = t / nty;
        const int tx = u2 % ntx; const int b = u2 / ntx;
        const int c0 = tx * 32, r0 = ty * 32;

        // ---- phase A: horizontal conv from prefetched regs -> LDS ----
        if (hasA) {
            float* srow = &s[a_tr][16 * a_oc8];
            #pragma unroll
            for (int d = 0; d < 8; ++d) {
                float lo = 0.f, hi = 0.f;
                #pragma unroll
                for (int k = 0; k < 8; ++k) {
                    const float x = va[2 * d + 9 - k];
                    lo += LOF[k] * x;
                    hi += HIF[k] * x;
                }
                *(float2*)(srow + 2 * d) = make_float2(lo, hi);
            }
        }
        __syncthreads();

        // ---- prefetch next tile's phase-A window (hidden under phase B) ----
        if (t + 1 < t_hi && hasA) {
            const int nt_ = t + 1;
            const int ty2 = nt_ % nty; const int u3 = nt_ / nty;
            const int tx2 = u3 % ntx; const int b2 = u3 / ntx;
            const float* Ain = in + b2 * inb;
            const int rr = 2 * (ty2 * 32) - 6 + a_tr;
            const int cw = 2 * (tx2 * 32) - 8 + 16 * a_oc8;
            if (rr >= 0 && rr < n && cw >= 0 && cw + 23 < n) {
                const float* p = Ain + rr * ldin + cw;
                #pragma unroll
                for (int j = 0; j < 6; ++j) {
                    const float4 t4 = *(const float4*)(p + 4 * j);
                    va[4*j] = t4.x; va[4*j+1] = t4.y; va[4*j+2] = t4.z; va[4*j+3] = t4.w;
                }
            } else {
                const float* row = Ain + refl(rr, n) * ldin;
                #pragma unroll
                for (int u = 0; u < 24; ++u) va[u] = row[refl(cw + u, n)];
            }
        }

        // ---- phase B: vertical conv from LDS -> 4 subbands ----
        const int ob = b * (m * m);
        const int oa = b * Ab;
        #pragma unroll
        for (int half = 0; half < 2; ++half) {
            const int idx = tid + half * NT;
            if (idx < 512) {
                const int c = idx & 31, pr = idx >> 5;
                float lov[10], hiv[10];
                #pragma unroll
                for (int j = 0; j < 10; ++j) {
                    const float2 w = *(const float2*)&s[4 * pr + j][2 * c];
                    lov[j] = w.x; hiv[j] = w.y;
                }
                float A0 = 0.f, H0 = 0.f, V0 = 0.f, D0 = 0.f;
                float A1 = 0.f, H1 = 0.f, V1 = 0.f, D1 = 0.f;
                #pragma unroll
                for (int k = 0; k < 8; ++k) {
                    const float l0 = lov[7 - k], h0 = hiv[7 - k];
                    const float l1 = lov[9 - k], h1 = hiv[9 - k];
                    A0 += LOF[k] * l0;  H0 += HIF[k] * l0;
                    V0 += LOF[k] * h0;  D0 += HIF[k] * h0;
                    A1 += LOF[k] * l1;  H1 += HIF[k] * l1;
                    V1 += LOF[k] * h1;  D1 += HIF[k] * h1;
                }
                const int gr = r0 + 2 * pr, gc = c0 + c;
                if (gc < m) {
                    const int od = gr * m + gc;
                    if (gr < m) {
                        oA[oa + gr * ldA + gc] = A0;
                        oH[ob + od] = H0; oV[ob + od] = V0; oD[ob + od] = D0;
                    }
                    if (gr + 1 < m) {
                        oA[oa + (gr + 1) * ldA + gc] = A1;
                        oH[ob + od + m] = H1; oV[ob + od + m] = V1; oD[ob + od + m] = D1;
                    }
                }
            }
        }
        __syncthreads();
    }
}

extern "C" void kernel_launch(void* const* d_in, const int* in_sizes, int n_in,
                              void* d_out, int out_size, void* d_ws, size_t ws_size,
                              hipStream_t stream) {
    const float* x = (const float*)d_in[0];
    float* out = (float*)d_out;
    float* ws  = (float*)d_ws;

    const int B = 16;
    const int n1 = 1024, m1 = 515;
    const int n2 = 515,  m2 = 261;
    const int n3 = 261,  m3 = 134;

    // padded cA intermediates (16B-aligned rows)
    const int ld1 = 516, b1 = m1 * ld1;
    const int ld2 = 264, b2 = m2 * ld2;
    float* a1 = ws;
    float* a2 = ws + (size_t)b1 * B;

    const size_t sz1 = (size_t)B * m1 * m1;
    const size_t sz2 = (size_t)B * m2 * m2;
    const size_t sz3 = (size_t)B * m3 * m3;

    // d_out: a3, lh3, hl3, hh3, lh2, hl2, hh2, lh1, hl1, hh1
    float* a3  = out;
    float* lh3 = a3  + sz3;
    float* hl3 = lh3 + sz3;
    float* hh3 = hl3 + sz3;
    float* lh2 = hh3 + sz3;
    float* hl2 = lh2 + sz2;
    float* hh2 = hl2 + sz2;
    float* lh1 = hh2 + sz2;
    float* hl1 = lh1 + sz1;
    float* hh1 = hl1 + sz1;

    const int t1 = (m1 + 31) / 32;   // 17
    const int t2_ = (m2 + 31) / 32;  // 9
    const int t3 = (m3 + 31) / 32;   // 5

    const int nt1 = t1 * t1 * B;     // 4624
    const int nt2 = t2_ * t2_ * B;   // 1296
    const int nt3 = t3 * t3 * B;     // 400

    const int G1 = 1536;             // 6 blocks/CU x 256 CU, ~3 tiles/block
    const int G2 = (nt2 < 1536) ? nt2 : 1536;
    const int G3 = (nt3 < 1536) ? nt3 : 1536;

    dim3 blk(NT);
    dwt2_fused<<<dim3(G1), blk, 0, stream>>>(x,  n1, n1, n1 * n1,
                                             m1, t1, t1, nt1,
                                             a1, ld1, b1, lh1, hl1, hh1);
    dwt2_fused<<<dim3(G2), blk, 0, stream>>>(a1, n2, ld1, b1,
                                             m2, t2_, t2_, nt2,
                                             a2, ld2, b2, lh2, hl2, hh2);
    dwt2_fused<<<dim3(G3), blk, 0, stream>>>(a2, n3, ld2, b2,
                                             m3, t3, t3, nt3,
                                             out, m3, m3 * m3, lh3, hl3, hh3);
}